// Round 12
// baseline (175.162 us; speedup 1.0000x reference)
//
#include <hip/hip_runtime.h>

#define HID 896
#define NH 14
#define NKV 2
#define NREP 7
#define SEQ 2048
#define BT 2
#define NTOK (BT*SEQ)
#define CSCALE 0.18033688011112042f   // (1/8) * log2(e), folded into Q at projection

typedef __attribute__((ext_vector_type(8))) short bf16x8;
typedef __attribute__((ext_vector_type(8))) unsigned short u16x8;
typedef __attribute__((ext_vector_type(4))) float fx4;
typedef __attribute__((ext_vector_type(4))) short s16x4;
typedef _Float16 f16x4 __attribute__((ext_vector_type(4)));
typedef __fp16 fp16x2 __attribute__((ext_vector_type(2)));

__device__ __forceinline__ unsigned short f2b(float x){
  union { float f; unsigned u; } a; a.f = x;
  unsigned r = a.u + 0x7FFFu + ((a.u >> 16) & 1u);   // RNE
  return (unsigned short)(r >> 16);
}
__device__ __forceinline__ unsigned short f2h(float x){
  union { _Float16 h; unsigned short u; } a; a.h = (_Float16)x; return a.u;
}
__device__ __forceinline__ u16x8 cvt8(float4 a, float4 b){
  u16x8 o;
  o[0]=f2b(a.x); o[1]=f2b(a.y); o[2]=f2b(a.z); o[3]=f2b(a.w);
  o[4]=f2b(b.x); o[5]=f2b(b.y); o[6]=f2b(b.z); o[7]=f2b(b.w);
  return o;
}

// ---------------- QKV projection GEMM (64x128, BK=64) — all-inline (no cvt kernel) --------
// A = hidden fp32 (converted during staging), B = Wq|Wk|Wv fp32 (block-uniform source,
// converted during staging). grid (64,9), block 256 (2x2 waves). RoPE inline sincosf.
// Q outputs pre-scaled by CSCALE.
__global__ __launch_bounds__(256) void qkv_gemm_kernel(
    const float* __restrict__ hidden,
    const float* __restrict__ Wq, const float* __restrict__ Wk, const float* __restrict__ Wv,
    const float* __restrict__ bq, const float* __restrict__ bk, const float* __restrict__ bv,
    const int* __restrict__ pos,
    unsigned short* __restrict__ qo, unsigned short* __restrict__ ko,
    unsigned short* __restrict__ vt)
{
  __shared__ short As[64*72];     // 9 KB
  __shared__ short Bs[128*72];    // 18 KB
  const int tid = threadIdx.x;
  const int bm = blockIdx.x, bn = blockIdx.y;
  const int w = tid >> 6, l = tid & 63, l15 = l & 15, q4 = l >> 4;
  const int wm = w >> 1, wn = w & 1;

  fx4 acc[2][4] = {};

  // block-uniform weight source: bn<7 -> Wq rows bn*128.. ; bn==7 -> Wk; bn==8 -> Wv
  const float* Wsrc = (bn < 7) ? Wq + (size_t)(bn*128)*HID : ((bn == 7) ? Wk : Wv);

  const int srow = tid >> 3, scol = (tid & 7)*8;   // srow 0..31
  const float* Agf = hidden + (size_t)(bm*64 + srow)*HID + scol;
  const float* Bgf = Wsrc + (size_t)srow*HID + scol;

  float4 a0[2], a1[2], b0[4], b1[4];
#pragma unroll
  for (int p = 0; p < 2; p++){
    a0[p] = *(const float4*)(Agf + (size_t)p*32*HID);
    a1[p] = *(const float4*)(Agf + (size_t)p*32*HID + 4);
  }
#pragma unroll
  for (int p = 0; p < 4; p++){
    b0[p] = *(const float4*)(Bgf + (size_t)p*32*HID);
    b1[p] = *(const float4*)(Bgf + (size_t)p*32*HID + 4);
  }

  for (int kt = 0; kt < 14; kt++){
#pragma unroll
    for (int p = 0; p < 2; p++)
      *(u16x8*)&As[(srow + p*32)*72 + scol] = cvt8(a0[p], a1[p]);
#pragma unroll
    for (int p = 0; p < 4; p++)
      *(u16x8*)&Bs[(srow + p*32)*72 + scol] = cvt8(b0[p], b1[p]);
    __syncthreads();
    if (kt < 13){
      const int ko_ = (kt+1)*64;
#pragma unroll
      for (int p = 0; p < 2; p++){
        a0[p] = *(const float4*)(Agf + (size_t)p*32*HID + ko_);
        a1[p] = *(const float4*)(Agf + (size_t)p*32*HID + ko_ + 4);
      }
#pragma unroll
      for (int p = 0; p < 4; p++){
        b0[p] = *(const float4*)(Bgf + (size_t)p*32*HID + ko_);
        b1[p] = *(const float4*)(Bgf + (size_t)p*32*HID + ko_ + 4);
      }
    }
#pragma unroll
    for (int ks = 0; ks < 2; ks++){
      bf16x8 af[2], bf[4];
#pragma unroll
      for (int mt = 0; mt < 2; mt++)
        af[mt] = *(bf16x8*)&As[(wm*32 + mt*16 + l15)*72 + ks*32 + q4*8];
#pragma unroll
      for (int nt = 0; nt < 4; nt++)
        bf[nt] = *(bf16x8*)&Bs[(wn*64 + nt*16 + l15)*72 + ks*32 + q4*8];
#pragma unroll
      for (int mt = 0; mt < 2; mt++)
#pragma unroll
        for (int nt = 0; nt < 4; nt++)
          acc[mt][nt] = __builtin_amdgcn_mfma_f32_16x16x32_bf16(af[mt], bf[nt], acc[mt][nt], 0,0,0);
    }
    __syncthreads();
  }

  const int hu = bn*2 + wn;
  const float* bias; int kind, hloc;
  if (hu < NH)      { bias = bq + hu*64;      kind = 0; hloc = hu; }
  else if (hu < 16) { bias = bk + (hu-NH)*64; kind = 1; hloc = hu-NH; }
  else              { bias = bv + (hu-16)*64; kind = 2; hloc = hu-16; }
  float bl[4];
#pragma unroll
  for (int nt = 0; nt < 4; nt++) bl[nt] = bias[nt*16 + l15];

  if (kind == 2){
#pragma unroll
    for (int mt = 0; mt < 2; mt++)
#pragma unroll
      for (int j = 0; j < 4; j++){
        int grow = bm*64 + wm*32 + mt*16 + q4*4 + j;
        int b = grow >> 11, s = grow & (SEQ-1);
        int tile = s >> 6, key = s & 63;
        unsigned short* dst = vt + (size_t)(((b*NKV + hloc)*(SEQ/64) + tile)*4096);
#pragma unroll
        for (int nt = 0; nt < 4; nt++)
          dst[(nt*16 + l15)*64 + key] = f2h(acc[mt][nt][j] + bl[nt]);
      }
  } else {
    const float qs = (kind == 0) ? CSCALE : 1.0f;
    float invf[2];
#pragma unroll
    for (int nt = 0; nt < 2; nt++)
      invf[nt] = exp2f(-(float)(nt*16 + l15) * 0.62286151779138041f);
#pragma unroll
    for (int mt = 0; mt < 2; mt++)
#pragma unroll
      for (int j = 0; j < 4; j++){
        int grow = bm*64 + wm*32 + mt*16 + q4*4 + j;
        int b = grow >> 11, s = grow & (SEQ-1);
        float p = (float)pos[grow];
        unsigned short* dst = (kind == 0)
            ? qo + ((size_t)(b*NH  + hloc)*SEQ + s)*64
            : ko + ((size_t)(b*NKV + hloc)*SEQ + s)*64;
        float x1 = acc[mt][0][j] + bl[0], x2 = acc[mt][2][j] + bl[2];
        float y1 = acc[mt][1][j] + bl[1], y2 = acc[mt][3][j] + bl[3];
        float s0v, c0v, s1v, c1v;
        sincosf(p*invf[0], &s0v, &c0v);
        sincosf(p*invf[1], &s1v, &c1v);
        dst[l15]      = f2b((x1*c0v - x2*s0v)*qs);
        dst[16 + l15] = f2b((y1*c1v - y2*s1v)*qs);
        dst[32 + l15] = f2b((x2*c0v + x1*s0v)*qs);
        dst[48 + l15] = f2b((y2*c1v + y1*s1v)*qs);
      }
  }
}

// -------- per-tile softmax + PV update (S^T orientation; CSCALE pre-folded into Q) --------
__device__ __forceinline__ void smax_pv(
    const fx4* s, bool diag, int wl, int q4,
    float& m_run, float& l_run, fx4* o, const f16x4 vf[4][4])
{
  float tv[16];
#pragma unroll
  for (int tl = 0; tl < 4; tl++)
#pragma unroll
    for (int j = 0; j < 4; j++){
      float x = s[tl][j];
      if (diag && (tl*16 + q4*4 + j > wl)) x = -1e30f;
      tv[tl*4+j] = x;
    }
  float mx = tv[0];
#pragma unroll
  for (int i = 1; i < 16; i++) mx = fmaxf(mx, tv[i]);
  mx = fmaxf(mx, __shfl_xor(mx, 16));
  mx = fmaxf(mx, __shfl_xor(mx, 32));
  float mn = fmaxf(m_run, mx);
  float al = exp2f(m_run - mn);
  m_run = mn;
  float p[16], rs = 0.f;
#pragma unroll
  for (int i = 0; i < 16; i++){ p[i] = exp2f(tv[i] - mn); rs += p[i]; }
  rs += __shfl_xor(rs, 16);
  rs += __shfl_xor(rs, 32);
  l_run = l_run*al + rs;
#pragma unroll
  for (int nt = 0; nt < 4; nt++)
#pragma unroll
    for (int j = 0; j < 4; j++) o[nt][j] *= al;
  f16x4 pf[4];
#pragma unroll
  for (int tl = 0; tl < 4; tl++){
    union { f16x4 v; fp16x2 h[2]; } u;
    u.h[0] = __builtin_amdgcn_cvt_pkrtz(p[tl*4+0], p[tl*4+1]);
    u.h[1] = __builtin_amdgcn_cvt_pkrtz(p[tl*4+2], p[tl*4+3]);
    pf[tl] = u.v;
  }
#pragma unroll
  for (int nt = 0; nt < 4; nt++)
#pragma unroll
    for (int tl = 0; tl < 4; tl++)
      o[nt] = __builtin_amdgcn_mfma_f32_16x16x16f16(vf[nt][tl], pf[tl], o[nt], 0,0,0);
}

// ---------------- flash attention (R7 paired + split-K; best measured 59.4us) ----------------
__global__ __launch_bounds__(512) void attn_kernel(
    const unsigned short* __restrict__ q, const unsigned short* __restrict__ k,
    const unsigned short* __restrict__ vt, unsigned short* __restrict__ ao)
{
  __shared__ short SB[4*64*72];
  short* KsB = SB;
  short* VtB = SB + 2*64*72;

  const int tid = threadIdx.x;
  const int w = tid >> 6, l = tid & 63, l15 = l & 15, q4 = l >> 4;
  const int g = w >> 2, wi = w & 3;
  const int tlo = blockIdx.x, thi = 31 - tlo;
  const int h = blockIdx.y, b = blockIdx.z, kvh = h / NREP;
  const int wl = wi*16 + l15;

  const unsigned short* qbase = q + ((size_t)(b*NH + h)*SEQ)*64;
  const unsigned short* qpA = qbase + (size_t)(thi*64 + wl)*64;
  const unsigned short* qpB = qbase + (size_t)(tlo*64 + wl)*64;
  bf16x8 qA0 = *(const bf16x8*)(qpA + q4*8), qA1 = *(const bf16x8*)(qpA + 32 + q4*8);
  bf16x8 qB0 = *(const bf16x8*)(qpB + q4*8), qB1 = *(const bf16x8*)(qpB + 32 + q4*8);

  fx4 oA[4] = {}, oB[4] = {};
  float mA = -1e30f, lA = 0.f, mB = -1e30f, lB = 0.f;

  const unsigned short* kbase = k  + ((size_t)(b*NKV + kvh)*SEQ)*64;
  const unsigned short* vbase = vt + (size_t)((b*NKV + kvh)*(SEQ/64))*4096;

  const int P = (thi + 2) >> 1;

  u16x8 kreg[2], vreg[2];
#pragma unroll
  for (int p = 0; p < 2; p++){
    int idx = p*512 + tid, tile = idx >> 9, off = idx & 511;
    kreg[p] = *(const u16x8*)(kbase + (size_t)tile*4096 + off*8);
    vreg[p] = *(const u16x8*)(vbase + (size_t)tile*4096 + off*8);
  }

  for (int si = 0; si < P; si++){
#pragma unroll
    for (int p = 0; p < 2; p++){
      int idx = p*512 + tid, tile = idx >> 9, off = idx & 511;
      int rr = off >> 3, g8 = off & 7;
      *(u16x8*)&KsB[tile*4608 + rr*72 + g8*8] = kreg[p];
      *(u16x8*)&VtB[tile*4608 + rr*72 + g8*8] = vreg[p];
    }
    __syncthreads();

    if (si + 1 < P){
      const int k0n = 2*(si+1);
#pragma unroll
      for (int p = 0; p < 2; p++){
        int idx = p*512 + tid, tile = idx >> 9, off = idx & 511;
        int tk = k0n + tile; if (tk > thi) tk = thi;
        kreg[p] = *(const u16x8*)(kbase + (size_t)tk*4096 + off*8);
        vreg[p] = *(const u16x8*)(vbase + (size_t)tk*4096 + off*8);
      }
    }

    const int kt = 2*si + g;
    if (kt <= thi){
      const short* Kst = KsB + g*4608;
      const short* Vtt = VtB + g*4608;
      bf16x8 kf0[4], kf1[4];
#pragma unroll
      for (int tl = 0; tl < 4; tl++){
        kf0[tl] = *(const bf16x8*)&Kst[(tl*16 + l15)*72 + q4*8];
        kf1[tl] = *(const bf16x8*)&Kst[(tl*16 + l15)*72 + 32 + q4*8];
      }
      f16x4 vf[4][4];
#pragma unroll
      for (int nt = 0; nt < 4; nt++)
#pragma unroll
        for (int tl = 0; tl < 4; tl++)
          vf[nt][tl] = *(const f16x4*)&Vtt[(nt*16 + l15)*72 + tl*16 + q4*4];

      {
        fx4 s[4] = {};
#pragma unroll
        for (int tl = 0; tl < 4; tl++){
          s[tl] = __builtin_amdgcn_mfma_f32_16x16x32_bf16(kf0[tl], qA0, s[tl], 0,0,0);
          s[tl] = __builtin_amdgcn_mfma_f32_16x16x32_bf16(kf1[tl], qA1, s[tl], 0,0,0);
        }
        smax_pv(s, kt == thi, wl, q4, mA, lA, oA, vf);
      }
      if (kt <= tlo){
        fx4 s[4] = {};
#pragma unroll
        for (int tl = 0; tl < 4; tl++){
          s[tl] = __builtin_amdgcn_mfma_f32_16x16x32_bf16(kf0[tl], qB0, s[tl], 0,0,0);
          s[tl] = __builtin_amdgcn_mfma_f32_16x16x32_bf16(kf1[tl], qB1, s[tl], 0,0,0);
        }
        smax_pv(s, kt == tlo, wl, q4, mB, lB, oB, vf);
      }
    }
    __syncthreads();
  }

  float* F = (float*)SB;
  if (g == 1){
    float* fa = F + (((wi*2 + 0)*64 + l)*18);
#pragma unroll
    for (int nt = 0; nt < 4; nt++)
#pragma unroll
      for (int j = 0; j < 4; j++) fa[nt*4 + j] = oA[nt][j];
    fa[16] = mA; fa[17] = lA;
    float* fb = F + (((wi*2 + 1)*64 + l)*18);
#pragma unroll
    for (int nt = 0; nt < 4; nt++)
#pragma unroll
      for (int j = 0; j < 4; j++) fb[nt*4 + j] = oB[nt][j];
    fb[16] = mB; fb[17] = lB;
  }
  __syncthreads();
  if (g == 0){
    {
      const float* fa = F + (((wi*2 + 0)*64 + l)*18);
      float m1 = fa[16], l1 = fa[17];
      float mM = fmaxf(mA, m1);
      float a0 = exp2f(mA - mM), a1 = exp2f(m1 - mM);
      lA = lA*a0 + l1*a1;
#pragma unroll
      for (int nt = 0; nt < 4; nt++)
#pragma unroll
        for (int j = 0; j < 4; j++) oA[nt][j] = oA[nt][j]*a0 + fa[nt*4+j]*a1;
    }
    {
      const float* fb = F + (((wi*2 + 1)*64 + l)*18);
      float m1 = fb[16], l1 = fb[17];
      float mM = fmaxf(mB, m1);
      float a0 = exp2f(mB - mM), a1 = exp2f(m1 - mM);
      lB = lB*a0 + l1*a1;
#pragma unroll
      for (int nt = 0; nt < 4; nt++)
#pragma unroll
        for (int j = 0; j < 4; j++) oB[nt][j] = oB[nt][j]*a0 + fb[nt*4+j]*a1;
    }
    {
      float inv = 1.0f / lA;
      unsigned short* dst = ao + ((size_t)(b*SEQ + thi*64 + wl))*HID + h*64;
#pragma unroll
      for (int nt = 0; nt < 4; nt++){
        s16x4 ov;
        ov[0] = (short)f2b(oA[nt][0]*inv); ov[1] = (short)f2b(oA[nt][1]*inv);
        ov[2] = (short)f2b(oA[nt][2]*inv); ov[3] = (short)f2b(oA[nt][3]*inv);
        *(s16x4*)(dst + nt*16 + q4*4) = ov;
      }
    }
    {
      float inv = 1.0f / lB;
      unsigned short* dst = ao + ((size_t)(b*SEQ + tlo*64 + wl))*HID + h*64;
#pragma unroll
      for (int nt = 0; nt < 4; nt++){
        s16x4 ov;
        ov[0] = (short)f2b(oB[nt][0]*inv); ov[1] = (short)f2b(oB[nt][1]*inv);
        ov[2] = (short)f2b(oB[nt][2]*inv); ov[3] = (short)f2b(oB[nt][3]*inv);
        *(s16x4*)(dst + nt*16 + q4*4) = ov;
      }
    }
  }
}

// ---------------- output projection GEMM (64x128, BK=64) — Wo fp32 inline convert ----------
// A = attn bf16 [4096,896], B = Wo fp32 [896,896] converted during staging. grid (64,7).
__global__ __launch_bounds__(256) void out_gemm_kernel(
    const unsigned short* __restrict__ A, const float* __restrict__ Wo,
    float* __restrict__ out)
{
  __shared__ short As[64*72];
  __shared__ short Bs[128*72];
  const int tid = threadIdx.x;
  const int bm = blockIdx.x, bn = blockIdx.y;
  const int w = tid >> 6, l = tid & 63, l15 = l & 15, q4 = l >> 4;
  const int wm = w >> 1, wn = w & 1;

  fx4 acc[2][4] = {};

  const int srow = tid >> 3, scol = (tid & 7)*8;
  const unsigned short* Ag = A + (size_t)(bm*64 + srow)*HID + scol;
  const float* Bgf = Wo + (size_t)(bn*128 + srow)*HID + scol;

  u16x8 ar[2]; float4 b0[4], b1[4];
#pragma unroll
  for (int p = 0; p < 2; p++) ar[p] = *(const u16x8*)(Ag + (size_t)p*32*HID);
#pragma unroll
  for (int p = 0; p < 4; p++){
    b0[p] = *(const float4*)(Bgf + (size_t)p*32*HID);
    b1[p] = *(const float4*)(Bgf + (size_t)p*32*HID + 4);
  }

  for (int kt = 0; kt < 14; kt++){
#pragma unroll
    for (int p = 0; p < 2; p++) *(u16x8*)&As[(srow + p*32)*72 + scol] = ar[p];
#pragma unroll
    for (int p = 0; p < 4; p++) *(u16x8*)&Bs[(srow + p*32)*72 + scol] = cvt8(b0[p], b1[p]);
    __syncthreads();
    if (kt < 13){
      const int ko_ = (kt+1)*64;
#pragma unroll
      for (int p = 0; p < 2; p++) ar[p] = *(const u16x8*)(Ag + (size_t)p*32*HID + ko_);
#pragma unroll
      for (int p = 0; p < 4; p++){
        b0[p] = *(const float4*)(Bgf + (size_t)p*32*HID + ko_);
        b1[p] = *(const float4*)(Bgf + (size_t)p*32*HID + ko_ + 4);
      }
    }
#pragma unroll
    for (int ks = 0; ks < 2; ks++){
      bf16x8 af[2], bf[4];
#pragma unroll
      for (int mt = 0; mt < 2; mt++)
        af[mt] = *(bf16x8*)&As[(wm*32 + mt*16 + l15)*72 + ks*32 + q4*8];
#pragma unroll
      for (int nt = 0; nt < 4; nt++)
        bf[nt] = *(bf16x8*)&Bs[(wn*64 + nt*16 + l15)*72 + ks*32 + q4*8];
#pragma unroll
      for (int mt = 0; mt < 2; mt++)
#pragma unroll
        for (int nt = 0; nt < 4; nt++)
          acc[mt][nt] = __builtin_amdgcn_mfma_f32_16x16x32_bf16(af[mt], bf[nt], acc[mt][nt], 0,0,0);
    }
    __syncthreads();
  }

#pragma unroll
  for (int mt = 0; mt < 2; mt++)
#pragma unroll
    for (int j = 0; j < 4; j++){
      int grow = bm*64 + wm*32 + mt*16 + q4*4 + j;
      float* dst = out + (size_t)grow*HID + bn*128 + wn*64;
#pragma unroll
      for (int nt = 0; nt < 4; nt++)
        dst[nt*16 + l15] = acc[mt][nt][j];
    }
}

extern "C" void kernel_launch(void* const* d_in, const int* in_sizes, int n_in,
                              void* d_out, int out_size, void* d_ws, size_t ws_size,
                              hipStream_t stream)
{
  const float* hidden = (const float*)d_in[0];
  const int*   pos    = (const int*)d_in[1];
  const float* Wq = (const float*)d_in[2]; const float* bq = (const float*)d_in[3];
  const float* Wk = (const float*)d_in[4]; const float* bk = (const float*)d_in[5];
  const float* Wv = (const float*)d_in[6]; const float* bv = (const float*)d_in[7];
  const float* Wo = (const float*)d_in[8];

  unsigned short* qws  = (unsigned short*)d_ws;                        // (B,NH,S,64) bf16 (Q pre-scaled)
  unsigned short* kws  = qws  + (size_t)BT*NH*SEQ*64;                  // (B,NKV,S,64) bf16
  unsigned short* vtws = kws  + (size_t)BT*NKV*SEQ*64;                 // (B,NKV,S/64,64,64) f16
  unsigned short* aws  = vtws + (size_t)BT*NKV*SEQ*64;                 // (B,S,896) bf16 attn-out

  qkv_gemm_kernel<<<dim3(NTOK/64, 9), 256, 0, stream>>>(
      hidden, Wq, Wk, Wv, bq, bk, bv, pos, qws, kws, vtws);

  attn_kernel<<<dim3(16, NH, BT), 512, 0, stream>>>(qws, kws, vtws, aws);

  out_gemm_kernel<<<dim3(NTOK/64, 7), 256, 0, stream>>>(aws, Wo, (float*)d_out);
}

// Round 13
// 173.548 us; speedup vs baseline: 1.0093x; 1.0093x over previous
//
#include <hip/hip_runtime.h>

#define HID 896
#define NH 14
#define NKV 2
#define NREP 7
#define SEQ 2048
#define BT 2
#define NTOK (BT*SEQ)
#define KT32 (HID/32)                 // 28 k-tiles of 32
#define CSCALE 0.18033688011112042f   // (1/8) * log2(e), folded into Q at projection

typedef __attribute__((ext_vector_type(8))) short bf16x8;
typedef __attribute__((ext_vector_type(8))) unsigned short u16x8;
typedef __attribute__((ext_vector_type(4))) float fx4;
typedef __attribute__((ext_vector_type(4))) short s16x4;
typedef _Float16 f16x4 __attribute__((ext_vector_type(4)));
typedef __fp16 fp16x2 __attribute__((ext_vector_type(2)));

__device__ __forceinline__ unsigned short f2b(float x){
  union { float f; unsigned u; } a; a.f = x;
  unsigned r = a.u + 0x7FFFu + ((a.u >> 16) & 1u);   // RNE
  return (unsigned short)(r >> 16);
}
__device__ __forceinline__ unsigned short f2h(float x){
  union { _Float16 h; unsigned short u; } a; a.h = (_Float16)x; return a.u;
}
__device__ __forceinline__ u16x8 cvt8(float4 a, float4 b){
  u16x8 o;
  o[0]=f2b(a.x); o[1]=f2b(a.y); o[2]=f2b(a.z); o[3]=f2b(a.w);
  o[4]=f2b(b.x); o[5]=f2b(b.y); o[6]=f2b(b.z); o[7]=f2b(b.w);
  return o;
}

// ------- fragment-packing cvt: fp32 -> bf16 in MFMA fragment order -------
// Packed layout: [16-row block][k-tile of 32][lane 0..63][8 bf16]; lane l holds
// src[row = blk*16 + (l&15)][k = kt*32 + (l>>4)*8 .. +8]  (A- and B-frag order).
// job 0: hidden (256 mb); job 1: Wq|Wk|Wv stacked (72 nb); job 2: Wo (56 nb).
__global__ __launch_bounds__(256) void cvt_pack_kernel(
    const float* __restrict__ hidden,
    const float* __restrict__ Wq, const float* __restrict__ Wk, const float* __restrict__ Wv,
    const float* __restrict__ Wo,
    unsigned short* __restrict__ apk, unsigned short* __restrict__ bpkq,
    unsigned short* __restrict__ bpko)
{
  const int job = blockIdx.y;
  const int n = (job == 0) ? 256*KT32*64 : (job == 1 ? 72*KT32*64 : 56*KT32*64);
  unsigned short* dst = (job == 0) ? apk : (job == 1 ? bpkq : bpko);

  for (int i = blockIdx.x*256 + threadIdx.x; i < n; i += gridDim.x*256){
    int l = i & 63, kt = (i >> 6) % KT32, blk = i / (KT32*64);
    int col = kt*32 + (l >> 4)*8;
    const float* src;
    if (job == 0){
      src = hidden + (size_t)(blk*16 + (l & 15))*HID + col;
    } else if (job == 1){
      const float* W; int r;
      if (blk < 56)      { W = Wq; r = blk*16; }
      else if (blk < 64) { W = Wk; r = (blk-56)*16; }
      else               { W = Wv; r = (blk-64)*16; }
      src = W + (size_t)(r + (l & 15))*HID + col;
    } else {
      src = Wo + (size_t)(blk*16 + (l & 15))*HID + col;
    }
    float4 a = *(const float4*)src;
    float4 b = *(const float4*)(src + 4);
    *(u16x8*)(dst + (size_t)i*8) = cvt8(a, b);
  }
}

// ---------------- QKV projection GEMM: barrier-free packed-fragment streaming ----------------
// A = packed hidden, B = packed WQKV. grid (64,9), block 256 (2x2 waves), ZERO LDS/barriers.
// Per k-step: 6 coalesced 1KB wave-loads + 8 MFMA, register-prefetched.
__global__ __launch_bounds__(256) void qkv_gemm_kernel(
    const unsigned short* __restrict__ Apk, const unsigned short* __restrict__ Bpk,
    const float* __restrict__ bq, const float* __restrict__ bk, const float* __restrict__ bv,
    const int* __restrict__ pos,
    unsigned short* __restrict__ qo, unsigned short* __restrict__ ko,
    unsigned short* __restrict__ vt)
{
  const int tid = threadIdx.x;
  const int bm = blockIdx.x, bn = blockIdx.y;
  const int w = tid >> 6, l = tid & 63, l15 = l & 15, q4 = l >> 4;
  const int wm = w >> 1, wn = w & 1;
  const int mb0 = bm*4 + wm*2, nb0 = bn*8 + wn*4;

  fx4 acc[2][4] = {};

  const unsigned short* Ab[2];
  const unsigned short* Bb[4];
#pragma unroll
  for (int mt = 0; mt < 2; mt++) Ab[mt] = Apk + ((size_t)(mb0+mt)*KT32)*512 + l*8;
#pragma unroll
  for (int nt = 0; nt < 4; nt++) Bb[nt] = Bpk + ((size_t)(nb0+nt)*KT32)*512 + l*8;

  bf16x8 ac[2], bc[4], an[2], bnx[4];
#pragma unroll
  for (int mt = 0; mt < 2; mt++) ac[mt] = *(const bf16x8*)(Ab[mt]);
#pragma unroll
  for (int nt = 0; nt < 4; nt++) bc[nt] = *(const bf16x8*)(Bb[nt]);

  for (int kt = 0; kt < KT32; kt++){
    if (kt < KT32-1){
      const int off = (kt+1)*512;
#pragma unroll
      for (int mt = 0; mt < 2; mt++) an[mt]  = *(const bf16x8*)(Ab[mt] + off);
#pragma unroll
      for (int nt = 0; nt < 4; nt++) bnx[nt] = *(const bf16x8*)(Bb[nt] + off);
    }
#pragma unroll
    for (int mt = 0; mt < 2; mt++)
#pragma unroll
      for (int nt = 0; nt < 4; nt++)
        acc[mt][nt] = __builtin_amdgcn_mfma_f32_16x16x32_bf16(ac[mt], bc[nt], acc[mt][nt], 0,0,0);
#pragma unroll
    for (int mt = 0; mt < 2; mt++) ac[mt] = an[mt];
#pragma unroll
    for (int nt = 0; nt < 4; nt++) bc[nt] = bnx[nt];
  }

  // ---- epilogue identical to R11/R12 (verified): bias + RoPE / V-tile pack ----
  const int hu = bn*2 + wn;
  const float* bias; int kind, hloc;
  if (hu < NH)      { bias = bq + hu*64;      kind = 0; hloc = hu; }
  else if (hu < 16) { bias = bk + (hu-NH)*64; kind = 1; hloc = hu-NH; }
  else              { bias = bv + (hu-16)*64; kind = 2; hloc = hu-16; }
  float bl[4];
#pragma unroll
  for (int nt = 0; nt < 4; nt++) bl[nt] = bias[nt*16 + l15];

  if (kind == 2){
#pragma unroll
    for (int mt = 0; mt < 2; mt++)
#pragma unroll
      for (int j = 0; j < 4; j++){
        int grow = bm*64 + wm*32 + mt*16 + q4*4 + j;
        int b = grow >> 11, s = grow & (SEQ-1);
        int tile = s >> 6, key = s & 63;
        unsigned short* dst = vt + (size_t)(((b*NKV + hloc)*(SEQ/64) + tile)*4096);
#pragma unroll
        for (int nt = 0; nt < 4; nt++)
          dst[(nt*16 + l15)*64 + key] = f2h(acc[mt][nt][j] + bl[nt]);
      }
  } else {
    const float qs = (kind == 0) ? CSCALE : 1.0f;
    float invf[2];
#pragma unroll
    for (int nt = 0; nt < 2; nt++)
      invf[nt] = exp2f(-(float)(nt*16 + l15) * 0.62286151779138041f);
#pragma unroll
    for (int mt = 0; mt < 2; mt++)
#pragma unroll
      for (int j = 0; j < 4; j++){
        int grow = bm*64 + wm*32 + mt*16 + q4*4 + j;
        int b = grow >> 11, s = grow & (SEQ-1);
        float p = (float)pos[grow];
        unsigned short* dst = (kind == 0)
            ? qo + ((size_t)(b*NH  + hloc)*SEQ + s)*64
            : ko + ((size_t)(b*NKV + hloc)*SEQ + s)*64;
        float x1 = acc[mt][0][j] + bl[0], x2 = acc[mt][2][j] + bl[2];
        float y1 = acc[mt][1][j] + bl[1], y2 = acc[mt][3][j] + bl[3];
        float s0v, c0v, s1v, c1v;
        sincosf(p*invf[0], &s0v, &c0v);
        sincosf(p*invf[1], &s1v, &c1v);
        dst[l15]      = f2b((x1*c0v - x2*s0v)*qs);
        dst[16 + l15] = f2b((y1*c1v - y2*s1v)*qs);
        dst[32 + l15] = f2b((x2*c0v + x1*s0v)*qs);
        dst[48 + l15] = f2b((y2*c1v + y1*s1v)*qs);
      }
  }
}

// -------- per-tile softmax + PV update (verified R3-R12) --------
__device__ __forceinline__ void smax_pv(
    const fx4* s, bool diag, int wl, int q4,
    float& m_run, float& l_run, fx4* o, const f16x4 vf[4][4])
{
  float tv[16];
#pragma unroll
  for (int tl = 0; tl < 4; tl++)
#pragma unroll
    for (int j = 0; j < 4; j++){
      float x = s[tl][j];
      if (diag && (tl*16 + q4*4 + j > wl)) x = -1e30f;
      tv[tl*4+j] = x;
    }
  float mx = tv[0];
#pragma unroll
  for (int i = 1; i < 16; i++) mx = fmaxf(mx, tv[i]);
  mx = fmaxf(mx, __shfl_xor(mx, 16));
  mx = fmaxf(mx, __shfl_xor(mx, 32));
  float mn = fmaxf(m_run, mx);
  float al = exp2f(m_run - mn);
  m_run = mn;
  float p[16], rs = 0.f;
#pragma unroll
  for (int i = 0; i < 16; i++){ p[i] = exp2f(tv[i] - mn); rs += p[i]; }
  rs += __shfl_xor(rs, 16);
  rs += __shfl_xor(rs, 32);
  l_run = l_run*al + rs;
#pragma unroll
  for (int nt = 0; nt < 4; nt++)
#pragma unroll
    for (int j = 0; j < 4; j++) o[nt][j] *= al;
  f16x4 pf[4];
#pragma unroll
  for (int tl = 0; tl < 4; tl++){
    union { f16x4 v; fp16x2 h[2]; } u;
    u.h[0] = __builtin_amdgcn_cvt_pkrtz(p[tl*4+0], p[tl*4+1]);
    u.h[1] = __builtin_amdgcn_cvt_pkrtz(p[tl*4+2], p[tl*4+3]);
    pf[tl] = u.v;
  }
#pragma unroll
  for (int nt = 0; nt < 4; nt++)
#pragma unroll
    for (int tl = 0; tl < 4; tl++)
      o[nt] = __builtin_amdgcn_mfma_f32_16x16x16f16(vf[nt][tl], pf[tl], o[nt], 0,0,0);
}

// write one O^T 16-row result in packed-A order for out_gemm
__device__ __forceinline__ void store_packedA(
    unsigned short* apk, int mb, int h, int q4, int l15, const fx4* o, float inv)
{
#pragma unroll
  for (int nt = 0; nt < 4; nt++){
    s16x4 ov;
    ov[0] = (short)f2b(o[nt][0]*inv); ov[1] = (short)f2b(o[nt][1]*inv);
    ov[2] = (short)f2b(o[nt][2]*inv); ov[3] = (short)f2b(o[nt][3]*inv);
    int ktile = h*2 + (nt >> 1);
    int flane = 16*((nt & 1)*2 + (q4 >> 1)) + l15;
    size_t addr = ((size_t)(mb*KT32 + ktile)*64 + flane)*8 + (q4 & 1)*4;
    *(s16x4*)(apk + addr) = ov;
  }
}

// ---------------- flash attention (R7 paired + split-K core; packed-A epilogue) ----------------
__global__ __launch_bounds__(512) void attn_kernel(
    const unsigned short* __restrict__ q, const unsigned short* __restrict__ k,
    const unsigned short* __restrict__ vt, unsigned short* __restrict__ apk)
{
  __shared__ short SB[4*64*72];
  short* KsB = SB;
  short* VtB = SB + 2*64*72;

  const int tid = threadIdx.x;
  const int w = tid >> 6, l = tid & 63, l15 = l & 15, q4 = l >> 4;
  const int g = w >> 2, wi = w & 3;
  const int tlo = blockIdx.x, thi = 31 - tlo;
  const int h = blockIdx.y, b = blockIdx.z, kvh = h / NREP;
  const int wl = wi*16 + l15;

  const unsigned short* qbase = q + ((size_t)(b*NH + h)*SEQ)*64;
  const unsigned short* qpA = qbase + (size_t)(thi*64 + wl)*64;
  const unsigned short* qpB = qbase + (size_t)(tlo*64 + wl)*64;
  bf16x8 qA0 = *(const bf16x8*)(qpA + q4*8), qA1 = *(const bf16x8*)(qpA + 32 + q4*8);
  bf16x8 qB0 = *(const bf16x8*)(qpB + q4*8), qB1 = *(const bf16x8*)(qpB + 32 + q4*8);

  fx4 oA[4] = {}, oB[4] = {};
  float mA = -1e30f, lA = 0.f, mB = -1e30f, lB = 0.f;

  const unsigned short* kbase = k  + ((size_t)(b*NKV + kvh)*SEQ)*64;
  const unsigned short* vbase = vt + (size_t)((b*NKV + kvh)*(SEQ/64))*4096;

  const int P = (thi + 2) >> 1;

  u16x8 kreg[2], vreg[2];
#pragma unroll
  for (int p = 0; p < 2; p++){
    int idx = p*512 + tid, tile = idx >> 9, off = idx & 511;
    kreg[p] = *(const u16x8*)(kbase + (size_t)tile*4096 + off*8);
    vreg[p] = *(const u16x8*)(vbase + (size_t)tile*4096 + off*8);
  }

  for (int si = 0; si < P; si++){
#pragma unroll
    for (int p = 0; p < 2; p++){
      int idx = p*512 + tid, tile = idx >> 9, off = idx & 511;
      int rr = off >> 3, g8 = off & 7;
      *(u16x8*)&KsB[tile*4608 + rr*72 + g8*8] = kreg[p];
      *(u16x8*)&VtB[tile*4608 + rr*72 + g8*8] = vreg[p];
    }
    __syncthreads();

    if (si + 1 < P){
      const int k0n = 2*(si+1);
#pragma unroll
      for (int p = 0; p < 2; p++){
        int idx = p*512 + tid, tile = idx >> 9, off = idx & 511;
        int tk = k0n + tile; if (tk > thi) tk = thi;
        kreg[p] = *(const u16x8*)(kbase + (size_t)tk*4096 + off*8);
        vreg[p] = *(const u16x8*)(vbase + (size_t)tk*4096 + off*8);
      }
    }

    const int kt = 2*si + g;
    if (kt <= thi){
      const short* Kst = KsB + g*4608;
      const short* Vtt = VtB + g*4608;
      bf16x8 kf0[4], kf1[4];
#pragma unroll
      for (int tl = 0; tl < 4; tl++){
        kf0[tl] = *(const bf16x8*)&Kst[(tl*16 + l15)*72 + q4*8];
        kf1[tl] = *(const bf16x8*)&Kst[(tl*16 + l15)*72 + 32 + q4*8];
      }
      f16x4 vf[4][4];
#pragma unroll
      for (int nt = 0; nt < 4; nt++)
#pragma unroll
        for (int tl = 0; tl < 4; tl++)
          vf[nt][tl] = *(const f16x4*)&Vtt[(nt*16 + l15)*72 + tl*16 + q4*4];

      {
        fx4 s[4] = {};
#pragma unroll
        for (int tl = 0; tl < 4; tl++){
          s[tl] = __builtin_amdgcn_mfma_f32_16x16x32_bf16(kf0[tl], qA0, s[tl], 0,0,0);
          s[tl] = __builtin_amdgcn_mfma_f32_16x16x32_bf16(kf1[tl], qA1, s[tl], 0,0,0);
        }
        smax_pv(s, kt == thi, wl, q4, mA, lA, oA, vf);
      }
      if (kt <= tlo){
        fx4 s[4] = {};
#pragma unroll
        for (int tl = 0; tl < 4; tl++){
          s[tl] = __builtin_amdgcn_mfma_f32_16x16x32_bf16(kf0[tl], qB0, s[tl], 0,0,0);
          s[tl] = __builtin_amdgcn_mfma_f32_16x16x32_bf16(kf1[tl], qB1, s[tl], 0,0,0);
        }
        smax_pv(s, kt == tlo, wl, q4, mB, lB, oB, vf);
      }
    }
    __syncthreads();
  }

  float* F = (float*)SB;
  if (g == 1){
    float* fa = F + (((wi*2 + 0)*64 + l)*18);
#pragma unroll
    for (int nt = 0; nt < 4; nt++)
#pragma unroll
      for (int j = 0; j < 4; j++) fa[nt*4 + j] = oA[nt][j];
    fa[16] = mA; fa[17] = lA;
    float* fb = F + (((wi*2 + 1)*64 + l)*18);
#pragma unroll
    for (int nt = 0; nt < 4; nt++)
#pragma unroll
      for (int j = 0; j < 4; j++) fb[nt*4 + j] = oB[nt][j];
    fb[16] = mB; fb[17] = lB;
  }
  __syncthreads();
  if (g == 0){
    {
      const float* fa = F + (((wi*2 + 0)*64 + l)*18);
      float m1 = fa[16], l1 = fa[17];
      float mM = fmaxf(mA, m1);
      float a0 = exp2f(mA - mM), a1 = exp2f(m1 - mM);
      lA = lA*a0 + l1*a1;
#pragma unroll
      for (int nt = 0; nt < 4; nt++)
#pragma unroll
        for (int j = 0; j < 4; j++) oA[nt][j] = oA[nt][j]*a0 + fa[nt*4+j]*a1;
    }
    {
      const float* fb = F + (((wi*2 + 1)*64 + l)*18);
      float m1 = fb[16], l1 = fb[17];
      float mM = fmaxf(mB, m1);
      float a0 = exp2f(mB - mM), a1 = exp2f(m1 - mM);
      lB = lB*a0 + l1*a1;
#pragma unroll
      for (int nt = 0; nt < 4; nt++)
#pragma unroll
        for (int j = 0; j < 4; j++) oB[nt][j] = oB[nt][j]*a0 + fb[nt*4+j]*a1;
    }
    store_packedA(apk, b*128 + thi*4 + wi, h, q4, l15, oA, 1.0f/lA);
    store_packedA(apk, b*128 + tlo*4 + wi, h, q4, l15, oB, 1.0f/lB);
  }
}

// ---------------- output projection GEMM: barrier-free packed streaming -> fp32 ----------------
// A = packed attn-out, B = packed Wo. grid (64,7), block 256, ZERO LDS/barriers.
__global__ __launch_bounds__(256) void out_gemm_kernel(
    const unsigned short* __restrict__ Apk, const unsigned short* __restrict__ Bpk,
    float* __restrict__ out)
{
  const int tid = threadIdx.x;
  const int bm = blockIdx.x, bn = blockIdx.y;
  const int w = tid >> 6, l = tid & 63, l15 = l & 15, q4 = l >> 4;
  const int wm = w >> 1, wn = w & 1;
  const int mb0 = bm*4 + wm*2, nb0 = bn*8 + wn*4;

  fx4 acc[2][4] = {};

  const unsigned short* Ab[2];
  const unsigned short* Bb[4];
#pragma unroll
  for (int mt = 0; mt < 2; mt++) Ab[mt] = Apk + ((size_t)(mb0+mt)*KT32)*512 + l*8;
#pragma unroll
  for (int nt = 0; nt < 4; nt++) Bb[nt] = Bpk + ((size_t)(nb0+nt)*KT32)*512 + l*8;

  bf16x8 ac[2], bc[4], an[2], bnx[4];
#pragma unroll
  for (int mt = 0; mt < 2; mt++) ac[mt] = *(const bf16x8*)(Ab[mt]);
#pragma unroll
  for (int nt = 0; nt < 4; nt++) bc[nt] = *(const bf16x8*)(Bb[nt]);

  for (int kt = 0; kt < KT32; kt++){
    if (kt < KT32-1){
      const int off = (kt+1)*512;
#pragma unroll
      for (int mt = 0; mt < 2; mt++) an[mt]  = *(const bf16x8*)(Ab[mt] + off);
#pragma unroll
      for (int nt = 0; nt < 4; nt++) bnx[nt] = *(const bf16x8*)(Bb[nt] + off);
    }
#pragma unroll
    for (int mt = 0; mt < 2; mt++)
#pragma unroll
      for (int nt = 0; nt < 4; nt++)
        acc[mt][nt] = __builtin_amdgcn_mfma_f32_16x16x32_bf16(ac[mt], bc[nt], acc[mt][nt], 0,0,0);
#pragma unroll
    for (int mt = 0; mt < 2; mt++) ac[mt] = an[mt];
#pragma unroll
    for (int nt = 0; nt < 4; nt++) bc[nt] = bnx[nt];
  }

#pragma unroll
  for (int mt = 0; mt < 2; mt++)
#pragma unroll
    for (int j = 0; j < 4; j++){
      int grow = bm*64 + wm*32 + mt*16 + q4*4 + j;
      float* dst = out + (size_t)grow*HID + bn*128 + wn*64;
#pragma unroll
      for (int nt = 0; nt < 4; nt++)
        dst[nt*16 + l15] = acc[mt][nt][j];
    }
}

extern "C" void kernel_launch(void* const* d_in, const int* in_sizes, int n_in,
                              void* d_out, int out_size, void* d_ws, size_t ws_size,
                              hipStream_t stream)
{
  const float* hidden = (const float*)d_in[0];
  const int*   pos    = (const int*)d_in[1];
  const float* Wq = (const float*)d_in[2]; const float* bq = (const float*)d_in[3];
  const float* Wk = (const float*)d_in[4]; const float* bk = (const float*)d_in[5];
  const float* Wv = (const float*)d_in[6]; const float* bv = (const float*)d_in[7];
  const float* Wo = (const float*)d_in[8];

  unsigned short* qws  = (unsigned short*)d_ws;                        // (B,NH,S,64) bf16 (Q pre-scaled)
  unsigned short* kws  = qws  + (size_t)BT*NH*SEQ*64;                  // (B,NKV,S,64) bf16
  unsigned short* vtws = kws  + (size_t)BT*NKV*SEQ*64;                 // (B,NKV,S/64,64,64) f16
  unsigned short* apk  = vtws + (size_t)BT*NKV*SEQ*64;                 // packed hidden, then packed attn-out
  unsigned short* bpkq = apk  + (size_t)NTOK*HID;                      // packed WQKV (1152x896)
  unsigned short* bpko = bpkq + (size_t)1152*HID;                      // packed Wo (896x896)

  cvt_pack_kernel<<<dim3(224, 3), 256, 0, stream>>>(
      hidden, Wq, Wk, Wv, Wo, apk, bpkq, bpko);

  qkv_gemm_kernel<<<dim3(NTOK/64, 9), 256, 0, stream>>>(
      apk, bpkq, bq, bk, bv, pos, qws, kws, vtws);

  attn_kernel<<<dim3(16, NH, BT), 512, 0, stream>>>(qws, kws, vtws, apk);

  out_gemm_kernel<<<dim3(NTOK/64, 7), 256, 0, stream>>>(apk, bpko, (float*)d_out);
}

// Round 15
// 164.287 us; speedup vs baseline: 1.0662x; 1.0564x over previous
//
#include <hip/hip_runtime.h>

#define HID 896
#define NH 14
#define NKV 2
#define NREP 7
#define SEQ 2048
#define BT 2
#define NTOK (BT*SEQ)
#define CSCALE 0.18033688011112042f   // (1/8) * log2(e), folded into Q at projection

typedef __attribute__((ext_vector_type(8))) short bf16x8;
typedef __attribute__((ext_vector_type(8))) unsigned short u16x8;
typedef __attribute__((ext_vector_type(4))) float fx4;
typedef __attribute__((ext_vector_type(4))) short s16x4;
typedef _Float16 f16x4 __attribute__((ext_vector_type(4)));
typedef __fp16 fp16x2 __attribute__((ext_vector_type(2)));

__device__ __forceinline__ unsigned short f2b(float x){
  union { float f; unsigned u; } a; a.f = x;
  unsigned r = a.u + 0x7FFFu + ((a.u >> 16) & 1u);   // RNE
  return (unsigned short)(r >> 16);
}
__device__ __forceinline__ unsigned short f2h(float x){
  union { _Float16 h; unsigned short u; } a; a.h = (_Float16)x; return a.u;
}

// async global->LDS, 16B/lane: LDS dst = wave-uniform base + lane*16 (m97 pattern).
// Used ONLY with full __syncthreads() (vmcnt(0) drain) — no custom waitcnt protocol.
__device__ __forceinline__ void gll16(const unsigned short* g, short* lds){
  __builtin_amdgcn_global_load_lds(
      (const __attribute__((address_space(1))) unsigned int*)(const void*)g,
      (__attribute__((address_space(3))) unsigned int*)(void*)lds, 16, 0, 0);
}

// ------- fp32->bf16 convert (jobs 0..4: hidden + weights) + RoPE table (job 5) -------
__global__ __launch_bounds__(256) void cvt_kernel(
    const float* __restrict__ s0, const float* __restrict__ s1,
    const float* __restrict__ s2, const float* __restrict__ s3,
    const float* __restrict__ s4,
    unsigned short* __restrict__ d0, unsigned short* __restrict__ d1,
    unsigned short* __restrict__ d2, unsigned short* __restrict__ d3,
    unsigned short* __restrict__ d4,
    int c0, int c1, int c2, int c3, int c4,
    float2* __restrict__ tab)
{
  if (blockIdx.y == 5){
    for (int i = blockIdx.x*256 + threadIdx.x; i < SEQ*32; i += gridDim.x*256){
      int s = i >> 5, d = i & 31;
      float f = (float)s * exp2f(-(float)d * 0.62286151779138041f);
      float sv, cv; sincosf(f, &sv, &cv);
      tab[i] = make_float2(cv, sv);
    }
    return;
  }
  const float* s; unsigned short* d; int c;
  switch (blockIdx.y){
    case 0: s=s0; d=d0; c=c0; break;
    case 1: s=s1; d=d1; c=c1; break;
    case 2: s=s2; d=d2; c=c2; break;
    case 3: s=s3; d=d3; c=c3; break;
    default: s=s4; d=d4; c=c4; break;
  }
  for (int i = (blockIdx.x*256 + threadIdx.x)*8; i < c; i += gridDim.x*2048){
    float4 a = *(const float4*)(s + i);
    float4 b = *(const float4*)(s + i + 4);
    u16x8 o;
    o[0]=f2b(a.x); o[1]=f2b(a.y); o[2]=f2b(a.z); o[3]=f2b(a.w);
    o[4]=f2b(b.x); o[5]=f2b(b.y); o[6]=f2b(b.z); o[7]=f2b(b.w);
    *(u16x8*)(d + i) = o;
  }
}

// ---------------- QKV projection GEMM (64x128, BK=64, gll16 + XOR swizzle) ----------------
// A = hidden bf16 [4096,896], B = WQKV bf16 [1152,896]. grid (64,9), block 256 (2x2 waves).
// Single-buffered, full __syncthreads() protocol (provably race-free; R10-measured 164.9us).
__global__ __launch_bounds__(256) void qkv_gemm_kernel(
    const unsigned short* __restrict__ A, const unsigned short* __restrict__ Bw,
    const float* __restrict__ bq, const float* __restrict__ bk, const float* __restrict__ bv,
    const int* __restrict__ pos, const float2* __restrict__ tab,
    unsigned short* __restrict__ qo, unsigned short* __restrict__ ko,
    unsigned short* __restrict__ vt)
{
  __shared__ short As[64*64];     // 8 KB
  __shared__ short Bs[128*64];    // 16 KB
  const int tid = threadIdx.x;
  const int bm = blockIdx.x, bn = blockIdx.y;
  const int w = tid >> 6, l = tid & 63, l15 = l & 15, q4 = l >> 4;
  const int wm = w >> 1, wn = w & 1;
  const int lr = l >> 3;                 // row-in-chunk 0..7
  const int cbg = (l & 7) ^ lr;          // swizzled global 16B-block
  const int sw = l15 & 7;                // frag-read swizzle key

  fx4 acc[2][4] = {};

  const unsigned short* Ag = A  + (size_t)(bm*64)*HID;
  const unsigned short* Bg = Bw + (size_t)(bn*128)*HID;

  for (int kt = 0; kt < 14; kt++){
    const int kc = kt*64 + cbg*8;
    // A: 8 chunks (1 KB each), 2 per wave; B: 16 chunks, 4 per wave
#pragma unroll
    for (int p = 0; p < 2; p++){
      int c = p*4 + w;
      gll16(Ag + (size_t)(c*8 + lr)*HID + kc, &As[c*512]);
    }
#pragma unroll
    for (int p = 0; p < 4; p++){
      int c = p*4 + w;
      gll16(Bg + (size_t)(c*8 + lr)*HID + kc, &Bs[c*512]);
    }
    __syncthreads();                     // drains vmcnt(0) -> LDS valid
#pragma unroll
    for (int ks = 0; ks < 2; ks++){
      bf16x8 af[2], bf[4];
#pragma unroll
      for (int mt = 0; mt < 2; mt++){
        int r = wm*32 + mt*16 + l15;
        af[mt] = *(bf16x8*)&As[r*64 + ((ks*4 + q4) ^ sw)*8];
      }
#pragma unroll
      for (int nt = 0; nt < 4; nt++){
        int r = wn*64 + nt*16 + l15;
        bf[nt] = *(bf16x8*)&Bs[r*64 + ((ks*4 + q4) ^ sw)*8];
      }
#pragma unroll
      for (int mt = 0; mt < 2; mt++)
#pragma unroll
        for (int nt = 0; nt < 4; nt++)
          acc[mt][nt] = __builtin_amdgcn_mfma_f32_16x16x32_bf16(af[mt], bf[nt], acc[mt][nt], 0,0,0);
    }
    __syncthreads();                     // protect LDS before next stage
  }

  const int hu = bn*2 + wn;
  const float* bias; int kind, hloc;
  if (hu < NH)      { bias = bq + hu*64;      kind = 0; hloc = hu; }
  else if (hu < 16) { bias = bk + (hu-NH)*64; kind = 1; hloc = hu-NH; }
  else              { bias = bv + (hu-16)*64; kind = 2; hloc = hu-16; }
  float bl[4];
#pragma unroll
  for (int nt = 0; nt < 4; nt++) bl[nt] = bias[nt*16 + l15];

  if (kind == 2){
#pragma unroll
    for (int mt = 0; mt < 2; mt++)
#pragma unroll
      for (int j = 0; j < 4; j++){
        int grow = bm*64 + wm*32 + mt*16 + q4*4 + j;
        int b = grow >> 11, s = grow & (SEQ-1);
        int tile = s >> 6, key = s & 63;
        unsigned short* dst = vt + (size_t)(((b*NKV + hloc)*(SEQ/64) + tile)*4096);
#pragma unroll
        for (int nt = 0; nt < 4; nt++)
          dst[(nt*16 + l15)*64 + key] = f2h(acc[mt][nt][j] + bl[nt]);
      }
  } else {
    const float qs = (kind == 0) ? CSCALE : 1.0f;
#pragma unroll
    for (int mt = 0; mt < 2; mt++)
#pragma unroll
      for (int j = 0; j < 4; j++){
        int grow = bm*64 + wm*32 + mt*16 + q4*4 + j;
        int b = grow >> 11, s = grow & (SEQ-1);
        int p = pos[grow];
        const float2* rp = tab + p*32 + l15;
        float2 cs0 = rp[0], cs1 = rp[16];
        unsigned short* dst = (kind == 0)
            ? qo + ((size_t)(b*NH  + hloc)*SEQ + s)*64
            : ko + ((size_t)(b*NKV + hloc)*SEQ + s)*64;
        float x1 = acc[mt][0][j] + bl[0], x2 = acc[mt][2][j] + bl[2];
        float y1 = acc[mt][1][j] + bl[1], y2 = acc[mt][3][j] + bl[3];
        dst[l15]      = f2b((x1*cs0.x - x2*cs0.y)*qs);
        dst[16 + l15] = f2b((y1*cs1.x - y2*cs1.y)*qs);
        dst[32 + l15] = f2b((x2*cs0.x + x1*cs0.y)*qs);
        dst[48 + l15] = f2b((y2*cs1.x + y1*cs1.y)*qs);
      }
  }
}

// -------- per-tile softmax + PV update (S^T orientation; CSCALE pre-folded into Q) --------
__device__ __forceinline__ void smax_pv(
    const fx4* s, bool diag, int wl, int q4,
    float& m_run, float& l_run, fx4* o, const f16x4 vf[4][4])
{
  float tv[16];
#pragma unroll
  for (int tl = 0; tl < 4; tl++)
#pragma unroll
    for (int j = 0; j < 4; j++){
      float x = s[tl][j];
      if (diag && (tl*16 + q4*4 + j > wl)) x = -1e30f;
      tv[tl*4+j] = x;
    }
  float mx = tv[0];
#pragma unroll
  for (int i = 1; i < 16; i++) mx = fmaxf(mx, tv[i]);
  mx = fmaxf(mx, __shfl_xor(mx, 16));
  mx = fmaxf(mx, __shfl_xor(mx, 32));
  float mn = fmaxf(m_run, mx);
  float al = exp2f(m_run - mn);
  m_run = mn;
  float p[16], rs = 0.f;
#pragma unroll
  for (int i = 0; i < 16; i++){ p[i] = exp2f(tv[i] - mn); rs += p[i]; }
  rs += __shfl_xor(rs, 16);
  rs += __shfl_xor(rs, 32);
  l_run = l_run*al + rs;
#pragma unroll
  for (int nt = 0; nt < 4; nt++)
#pragma unroll
    for (int j = 0; j < 4; j++) o[nt][j] *= al;
  f16x4 pf[4];
#pragma unroll
  for (int tl = 0; tl < 4; tl++){
    union { f16x4 v; fp16x2 h[2]; } u;
    u.h[0] = __builtin_amdgcn_cvt_pkrtz(p[tl*4+0], p[tl*4+1]);
    u.h[1] = __builtin_amdgcn_cvt_pkrtz(p[tl*4+2], p[tl*4+3]);
    pf[tl] = u.v;
  }
#pragma unroll
  for (int nt = 0; nt < 4; nt++)
#pragma unroll
    for (int tl = 0; tl < 4; tl++)
      o[nt] = __builtin_amdgcn_mfma_f32_16x16x16f16(vf[nt][tl], pf[tl], o[nt], 0,0,0);
}

// ---------------- flash attention (R7 paired + split-K; best measured 59.4us) ----------------
__global__ __launch_bounds__(512) void attn_kernel(
    const unsigned short* __restrict__ q, const unsigned short* __restrict__ k,
    const unsigned short* __restrict__ vt, unsigned short* __restrict__ ao)
{
  __shared__ short SB[4*64*72];
  short* KsB = SB;
  short* VtB = SB + 2*64*72;

  const int tid = threadIdx.x;
  const int w = tid >> 6, l = tid & 63, l15 = l & 15, q4 = l >> 4;
  const int g = w >> 2, wi = w & 3;
  const int tlo = blockIdx.x, thi = 31 - tlo;
  const int h = blockIdx.y, b = blockIdx.z, kvh = h / NREP;
  const int wl = wi*16 + l15;

  const unsigned short* qbase = q + ((size_t)(b*NH + h)*SEQ)*64;
  const unsigned short* qpA = qbase + (size_t)(thi*64 + wl)*64;
  const unsigned short* qpB = qbase + (size_t)(tlo*64 + wl)*64;
  bf16x8 qA0 = *(const bf16x8*)(qpA + q4*8), qA1 = *(const bf16x8*)(qpA + 32 + q4*8);
  bf16x8 qB0 = *(const bf16x8*)(qpB + q4*8), qB1 = *(const bf16x8*)(qpB + 32 + q4*8);

  fx4 oA[4] = {}, oB[4] = {};
  float mA = -1e30f, lA = 0.f, mB = -1e30f, lB = 0.f;

  const unsigned short* kbase = k  + ((size_t)(b*NKV + kvh)*SEQ)*64;
  const unsigned short* vbase = vt + (size_t)((b*NKV + kvh)*(SEQ/64))*4096;

  const int P = (thi + 2) >> 1;

  u16x8 kreg[2], vreg[2];
#pragma unroll
  for (int p = 0; p < 2; p++){
    int idx = p*512 + tid, tile = idx >> 9, off = idx & 511;
    kreg[p] = *(const u16x8*)(kbase + (size_t)tile*4096 + off*8);
    vreg[p] = *(const u16x8*)(vbase + (size_t)tile*4096 + off*8);
  }

  for (int si = 0; si < P; si++){
#pragma unroll
    for (int p = 0; p < 2; p++){
      int idx = p*512 + tid, tile = idx >> 9, off = idx & 511;
      int rr = off >> 3, g8 = off & 7;
      *(u16x8*)&KsB[tile*4608 + rr*72 + g8*8] = kreg[p];
      *(u16x8*)&VtB[tile*4608 + rr*72 + g8*8] = vreg[p];
    }
    __syncthreads();

    if (si + 1 < P){
      const int k0n = 2*(si+1);
#pragma unroll
      for (int p = 0; p < 2; p++){
        int idx = p*512 + tid, tile = idx >> 9, off = idx & 511;
        int tk = k0n + tile; if (tk > thi) tk = thi;
        kreg[p] = *(const u16x8*)(kbase + (size_t)tk*4096 + off*8);
        vreg[p] = *(const u16x8*)(vbase + (size_t)tk*4096 + off*8);
      }
    }

    const int kt = 2*si + g;
    if (kt <= thi){
      const short* Kst = KsB + g*4608;
      const short* Vtt = VtB + g*4608;
      bf16x8 kf0[4], kf1[4];
#pragma unroll
      for (int tl = 0; tl < 4; tl++){
        kf0[tl] = *(const bf16x8*)&Kst[(tl*16 + l15)*72 + q4*8];
        kf1[tl] = *(const bf16x8*)&Kst[(tl*16 + l15)*72 + 32 + q4*8];
      }
      f16x4 vf[4][4];
#pragma unroll
      for (int nt = 0; nt < 4; nt++)
#pragma unroll
        for (int tl = 0; tl < 4; tl++)
          vf[nt][tl] = *(const f16x4*)&Vtt[(nt*16 + l15)*72 + tl*16 + q4*4];

      {
        fx4 s[4] = {};
#pragma unroll
        for (int tl = 0; tl < 4; tl++){
          s[tl] = __builtin_amdgcn_mfma_f32_16x16x32_bf16(kf0[tl], qA0, s[tl], 0,0,0);
          s[tl] = __builtin_amdgcn_mfma_f32_16x16x32_bf16(kf1[tl], qA1, s[tl], 0,0,0);
        }
        smax_pv(s, kt == thi, wl, q4, mA, lA, oA, vf);
      }
      if (kt <= tlo){
        fx4 s[4] = {};
#pragma unroll
        for (int tl = 0; tl < 4; tl++){
          s[tl] = __builtin_amdgcn_mfma_f32_16x16x32_bf16(kf0[tl], qB0, s[tl], 0,0,0);
          s[tl] = __builtin_amdgcn_mfma_f32_16x16x32_bf16(kf1[tl], qB1, s[tl], 0,0,0);
        }
        smax_pv(s, kt == tlo, wl, q4, mB, lB, oB, vf);
      }
    }
    __syncthreads();
  }

  float* F = (float*)SB;
  if (g == 1){
    float* fa = F + (((wi*2 + 0)*64 + l)*18);
#pragma unroll
    for (int nt = 0; nt < 4; nt++)
#pragma unroll
      for (int j = 0; j < 4; j++) fa[nt*4 + j] = oA[nt][j];
    fa[16] = mA; fa[17] = lA;
    float* fb = F + (((wi*2 + 1)*64 + l)*18);
#pragma unroll
    for (int nt = 0; nt < 4; nt++)
#pragma unroll
      for (int j = 0; j < 4; j++) fb[nt*4 + j] = oB[nt][j];
    fb[16] = mB; fb[17] = lB;
  }
  __syncthreads();
  if (g == 0){
    {
      const float* fa = F + (((wi*2 + 0)*64 + l)*18);
      float m1 = fa[16], l1 = fa[17];
      float mM = fmaxf(mA, m1);
      float a0 = exp2f(mA - mM), a1 = exp2f(m1 - mM);
      lA = lA*a0 + l1*a1;
#pragma unroll
      for (int nt = 0; nt < 4; nt++)
#pragma unroll
        for (int j = 0; j < 4; j++) oA[nt][j] = oA[nt][j]*a0 + fa[nt*4+j]*a1;
    }
    {
      const float* fb = F + (((wi*2 + 1)*64 + l)*18);
      float m1 = fb[16], l1 = fb[17];
      float mM = fmaxf(mB, m1);
      float a0 = exp2f(mB - mM), a1 = exp2f(m1 - mM);
      lB = lB*a0 + l1*a1;
#pragma unroll
      for (int nt = 0; nt < 4; nt++)
#pragma unroll
        for (int j = 0; j < 4; j++) oB[nt][j] = oB[nt][j]*a0 + fb[nt*4+j]*a1;
    }
    {
      float inv = 1.0f / lA;
      unsigned short* dst = ao + ((size_t)(b*SEQ + thi*64 + wl))*HID + h*64;
#pragma unroll
      for (int nt = 0; nt < 4; nt++){
        s16x4 ov;
        ov[0] = (short)f2b(oA[nt][0]*inv); ov[1] = (short)f2b(oA[nt][1]*inv);
        ov[2] = (short)f2b(oA[nt][2]*inv); ov[3] = (short)f2b(oA[nt][3]*inv);
        *(s16x4*)(dst + nt*16 + q4*4) = ov;
      }
    }
    {
      float inv = 1.0f / lB;
      unsigned short* dst = ao + ((size_t)(b*SEQ + tlo*64 + wl))*HID + h*64;
#pragma unroll
      for (int nt = 0; nt < 4; nt++){
        s16x4 ov;
        ov[0] = (short)f2b(oB[nt][0]*inv); ov[1] = (short)f2b(oB[nt][1]*inv);
        ov[2] = (short)f2b(oB[nt][2]*inv); ov[3] = (short)f2b(oB[nt][3]*inv);
        *(s16x4*)(dst + nt*16 + q4*4) = ov;
      }
    }
  }
}

// ---------------- output projection GEMM (64x128, BK=64, gll16 + swizzle) ----------------
// A = attn bf16 [4096,896], B = Wo bf16 [896,896]. grid (64, 7), block 256.
__global__ __launch_bounds__(256) void out_gemm_kernel(
    const unsigned short* __restrict__ A, const unsigned short* __restrict__ Bw,
    float* __restrict__ out)
{
  __shared__ short As[64*64];
  __shared__ short Bs[128*64];
  const int tid = threadIdx.x;
  const int bm = blockIdx.x, bn = blockIdx.y;
  const int w = tid >> 6, l = tid & 63, l15 = l & 15, q4 = l >> 4;
  const int wm = w >> 1, wn = w & 1;
  const int lr = l >> 3;
  const int cbg = (l & 7) ^ lr;
  const int sw = l15 & 7;

  fx4 acc[2][4] = {};

  const unsigned short* Ag = A  + (size_t)(bm*64)*HID;
  const unsigned short* Bg = Bw + (size_t)(bn*128)*HID;

  for (int kt = 0; kt < 14; kt++){
    const int kc = kt*64 + cbg*8;
#pragma unroll
    for (int p = 0; p < 2; p++){
      int c = p*4 + w;
      gll16(Ag + (size_t)(c*8 + lr)*HID + kc, &As[c*512]);
    }
#pragma unroll
    for (int p = 0; p < 4; p++){
      int c = p*4 + w;
      gll16(Bg + (size_t)(c*8 + lr)*HID + kc, &Bs[c*512]);
    }
    __syncthreads();
#pragma unroll
    for (int ks = 0; ks < 2; ks++){
      bf16x8 af[2], bf[4];
#pragma unroll
      for (int mt = 0; mt < 2; mt++){
        int r = wm*32 + mt*16 + l15;
        af[mt] = *(bf16x8*)&As[r*64 + ((ks*4 + q4) ^ sw)*8];
      }
#pragma unroll
      for (int nt = 0; nt < 4; nt++){
        int r = wn*64 + nt*16 + l15;
        bf[nt] = *(bf16x8*)&Bs[r*64 + ((ks*4 + q4) ^ sw)*8];
      }
#pragma unroll
      for (int mt = 0; mt < 2; mt++)
#pragma unroll
        for (int nt = 0; nt < 4; nt++)
          acc[mt][nt] = __builtin_amdgcn_mfma_f32_16x16x32_bf16(af[mt], bf[nt], acc[mt][nt], 0,0,0);
    }
    __syncthreads();
  }

#pragma unroll
  for (int mt = 0; mt < 2; mt++)
#pragma unroll
    for (int j = 0; j < 4; j++){
      int grow = bm*64 + wm*32 + mt*16 + q4*4 + j;
      float* dst = out + (size_t)grow*HID + bn*128 + wn*64;
#pragma unroll
      for (int nt = 0; nt < 4; nt++)
        dst[nt*16 + l15] = acc[mt][nt][j];
    }
}

extern "C" void kernel_launch(void* const* d_in, const int* in_sizes, int n_in,
                              void* d_out, int out_size, void* d_ws, size_t ws_size,
                              hipStream_t stream)
{
  const float* hidden = (const float*)d_in[0];
  const int*   pos    = (const int*)d_in[1];
  const float* Wq = (const float*)d_in[2]; const float* bq = (const float*)d_in[3];
  const float* Wk = (const float*)d_in[4]; const float* bk = (const float*)d_in[5];
  const float* Wv = (const float*)d_in[6]; const float* bv = (const float*)d_in[7];
  const float* Wo = (const float*)d_in[8];

  unsigned short* qws   = (unsigned short*)d_ws;                       // (B,NH,S,64) bf16 (Q pre-scaled)
  unsigned short* kws   = qws   + (size_t)BT*NH*SEQ*64;                // (B,NKV,S,64) bf16
  unsigned short* vtws  = kws   + (size_t)BT*NKV*SEQ*64;               // (B,NKV,S/64,64,64) f16
  unsigned short* wqkv  = vtws  + (size_t)BT*NKV*SEQ*64;               // (1152,896) bf16
  unsigned short* wo16  = wqkv  + (size_t)1152*HID;                    // (896,896) bf16
  unsigned short* h16   = wo16  + (size_t)HID*HID;                     // (4096,896) bf16: hidden, then attn-out
  float2*         tab   = (float2*)(h16 + (size_t)NTOK*HID);           // (2048,32) rope table

  const int nh   = NTOK*HID;
  const int nwq  = HID*HID;
  const int nwkv = 2*64*HID;

  cvt_kernel<<<dim3(448, 6), 256, 0, stream>>>(
      hidden, Wq, Wk, Wv, Wo,
      h16, wqkv, wqkv + nwq, wqkv + nwq + nwkv, wo16,
      nh, nwq, nwkv, nwkv, nwq, tab);

  qkv_gemm_kernel<<<dim3(NTOK/64, 9), 256, 0, stream>>>(
      h16, wqkv, bq, bk, bv, pos, tab, qws, kws, vtws);

  attn_kernel<<<dim3(16, NH, BT), 512, 0, stream>>>(qws, kws, vtws, h16);

  out_gemm_kernel<<<dim3(NTOK/64, 7), 256, 0, stream>>>(h16, wo16, (float*)d_out);
}